// Round 4
// baseline (213.331 us; speedup 1.0000x reference)
//
#include <hip/hip_runtime.h>
#include <hip/hip_fp16.h>

#define Mpts 32768
#define Vv 9
#define Cc 24
#define Hh 120
#define Ww 160
#define Npts (Mpts * 8)          // 262144
#define PIX (Hh * Ww)            // 19200
#define VOXEL 0.04f

// ---------------- workspace layout (bytes) ----------------
// [0,64)    : 3 doubles: sum_z, sum_z2, pos_cnt (zeroed by prep)
// OFF_TF    : tf = feats (V,H,W) x 32B/pixel fp8(24ch+8pad) : 5529600 B
// OFF_PREH  : pre_h (M,24) f32                               : 3145728 B
// OFF_HP    : hp (12,N) uint (= half2 channel pairs)         : 12582912 B
// OFF_Z     : zbuf (N) f32                                   : 1048576 B
#define OFF_TF    64
#define OFF_PREH  (OFF_TF + Vv * PIX * 32)
#define OFF_HP    (OFF_PREH + Mpts * Cc * 4)
#define OFF_Z     (OFF_HP + Npts * Cc * 2)

typedef __attribute__((ext_vector_type(2))) float f32x2;

__device__ __forceinline__ unsigned pack2h(float a, float b) {
  __half2 h = __floats2half2_rn(a, b);
  return *(unsigned*)&h;
}

// pack 4 floats -> 4 fp8 e4m3 in one uint
__device__ __forceinline__ unsigned pack4fp8(float a, float b, float c,
                                             float d) {
  int u = __builtin_amdgcn_cvt_pk_fp8_f32(a, b, 0, false);
  u = __builtin_amdgcn_cvt_pk_fp8_f32(c, d, u, true);
  return (unsigned)u;
}

// ---------------- 1) prep: feats -> fp8 (V,H,W,32B), pre_h, zero red -------
__global__ __launch_bounds__(256) void prep_kernel(
    const float* __restrict__ feats, const float* __restrict__ pre_feat,
    const float* __restrict__ W_sp, const float* __restrict__ b_sp,
    uint4* __restrict__ tf, float* __restrict__ pre_h,
    double* __restrict__ red) {
  __shared__ float tile[64][Cc + 1];
  __shared__ float Wl[50 * Cc];
  __shared__ float bl[Cc];
  int blk = blockIdx.x;
  if (blk == 0 && threadIdx.x < 3) red[threadIdx.x] = 0.0;

  if (blk < Vv * 300) {
    int v = blk / 300;
    int p0 = (blk % 300) * 64;
    const float* src = feats + (size_t)v * (Cc * PIX);
    for (int i = threadIdx.x; i < Cc * 64; i += 256) {
      int c = i >> 6, p = i & 63;
      tile[p][c] = src[c * PIX + p0 + p];
    }
    __syncthreads();
    uint4* dst = tf + ((size_t)v * PIX + p0) * 2;
    if (threadIdx.x < 128) {
      int p = threadIdx.x >> 1, sel = threadIdx.x & 1;
      const float* t = &tile[p][0];
      uint4 u;
      if (sel == 0) {
        u.x = pack4fp8(t[0], t[1], t[2], t[3]);
        u.y = pack4fp8(t[4], t[5], t[6], t[7]);
        u.z = pack4fp8(t[8], t[9], t[10], t[11]);
        u.w = pack4fp8(t[12], t[13], t[14], t[15]);
      } else {
        u.x = pack4fp8(t[16], t[17], t[18], t[19]);
        u.y = pack4fp8(t[20], t[21], t[22], t[23]);
        u.z = 0;
        u.w = 0;
      }
      dst[p * 2 + sel] = u;
    }
  } else {
    int mb = blk - Vv * 300;
    for (int i = threadIdx.x; i < 50 * Cc; i += 256) Wl[i] = W_sp[25 * Cc + i];
    if (threadIdx.x < Cc) bl[threadIdx.x] = b_sp[threadIdx.x];
    __syncthreads();
    int m = mb * 256 + threadIdx.x;
    float acc[Cc];
#pragma unroll
    for (int j = 0; j < Cc; j++) acc[j] = bl[j];
    const float* pf = pre_feat + (size_t)m * 50;
    for (int k = 0; k < 50; k++) {
      float x = pf[k];
#pragma unroll
      for (int j = 0; j < Cc; j++) acc[j] += x * Wl[k * Cc + j];
    }
    float* o = pre_h + (size_t)m * Cc;
#pragma unroll
    for (int j = 0; j < Cc; j++) o[j] = acc[j];
  }
}

// acc[0..15] += w * fp8x16(A)
__device__ __forceinline__ void acc16(uint4 A, float w, float* acc) {
#pragma unroll
  for (int t = 0; t < 4; t++) {
    unsigned u = ((const unsigned*)&A)[t];
    f32x2 f0 = __builtin_amdgcn_cvt_pk_f32_fp8((int)u, false);
    f32x2 f1 = __builtin_amdgcn_cvt_pk_f32_fp8((int)u, true);
    acc[4 * t + 0] += w * f0.x;
    acc[4 * t + 1] += w * f0.y;
    acc[4 * t + 2] += w * f1.x;
    acc[4 * t + 3] += w * f1.y;
  }
}
// acc[0..7] += w * fp8x8(ux,uy)
__device__ __forceinline__ void acc8(unsigned ux, unsigned uy, float w,
                                     float* acc) {
  f32x2 f0 = __builtin_amdgcn_cvt_pk_f32_fp8((int)ux, false);
  f32x2 f1 = __builtin_amdgcn_cvt_pk_f32_fp8((int)ux, true);
  f32x2 f2 = __builtin_amdgcn_cvt_pk_f32_fp8((int)uy, false);
  f32x2 f3 = __builtin_amdgcn_cvt_pk_f32_fp8((int)uy, true);
  acc[0] += w * f0.x;
  acc[1] += w * f0.y;
  acc[2] += w * f1.x;
  acc[3] += w * f1.y;
  acc[4] += w * f2.x;
  acc[5] += w * f2.y;
  acc[6] += w * f3.x;
  acc[7] += w * f3.y;
}

// ---------------- 2) main: project + sample + h-partial + reduction --------
__global__ __launch_bounds__(256, 4) void main_kernel(
    const int* __restrict__ pre_coords, const uint4* __restrict__ tfq,
    const float* __restrict__ KRcam, const float* __restrict__ vol_origin,
    const float* __restrict__ w2ac, const float* __restrict__ W_sp,
    const float* __restrict__ pre_h, float* __restrict__ out,
    unsigned* __restrict__ hp, float* __restrict__ zbuf,
    double* __restrict__ red) {
  __shared__ float KR[Vv * 12];
  __shared__ float Wl[Cc * Cc];      // W_sp[0:24,:]
  __shared__ float w2a[12];
  __shared__ float orig[3];
  __shared__ float redl[3][4];
  for (int i = threadIdx.x; i < Vv * 12; i += 256) {
    int v = i / 12, r = i - v * 12;
    KR[i] = KRcam[v * 16 + r];
  }
  for (int i = threadIdx.x; i < Cc * Cc; i += 256) Wl[i] = W_sp[i];
  if (threadIdx.x < 12) w2a[threadIdx.x] = w2ac[threadIdx.x];
  if (threadIdx.x < 3) orig[threadIdx.x] = vol_origin[threadIdx.x];
  __syncthreads();

  int n = blockIdx.x * 256 + threadIdx.x;
  int m = n >> 3, o = n & 7;
  int cx = pre_coords[m * 4 + 1] + ((0xB2 >> o) & 1);
  int cy = pre_coords[m * 4 + 2] + ((0xD4 >> o) & 1);
  int cz = pre_coords[m * 4 + 3] + ((0xE8 >> o) & 1);
  float wx0 = (float)cx * VOXEL + orig[0];
  float wy0 = (float)cy * VOXEL + orig[1];
  float wz0 = (float)cz * VOXEL + orig[2];

  {  // r_coords
    float camx = w2a[0] * wx0 + w2a[1] * wy0 + w2a[2] * wz0 + w2a[3];
    float camy = w2a[4] * wx0 + w2a[5] * wy0 + w2a[6] * wz0 + w2a[7];
    float camz = w2a[8] * wx0 + w2a[9] * wy0 + w2a[10] * wz0 + w2a[11];
    float4 rc = make_float4(camx, camy, camz, (float)pre_coords[m * 4 + 0]);
    ((float4*)(out + 3 * Npts))[n] = rc;
  }

  float acc[Cc];
#pragma unroll
  for (int c = 0; c < Cc; c++) acc[c] = 0.f;
  float zsum = 0.f;
  float cntf = 0.f;

#pragma unroll 3
  for (int v = 0; v < Vv; v++) {
    const float* kr = &KR[v * 12];
    float ix = kr[0] * wx0 + kr[1] * wy0 + kr[2] * wz0 + kr[3];
    float iy = kr[4] * wx0 + kr[5] * wy0 + kr[6] * wz0 + kr[7];
    float iz = kr[8] * wx0 + kr[9] * wy0 + kr[10] * wz0 + kr[11];
    float sz = (fabsf(iz) > 1e-9f) ? iz : 1e-9f;
    float px = ix / sz;
    float py = iy / sz;
    float mf = ((px >= 0.f) && (px <= (float)(Ww - 1)) && (py >= 0.f) &&
                (py <= (float)(Hh - 1)) && (iz > 0.f))
                   ? 1.f
                   : 0.f;
    float pxc = fminf(fmaxf(px, 0.f), (float)(Ww - 1));
    float pyc = fminf(fmaxf(py, 0.f), (float)(Hh - 1));
    float xsf = fminf(floorf(pxc), (float)(Ww - 2));
    float ysf = fminf(floorf(pyc), (float)(Hh - 2));
    float wx = pxc - xsf, wy = pyc - ysf;
    int xs = (int)xsf, ys = (int)ysf;
    float w00 = (1.f - wx) * (1.f - wy) * mf;
    float w10 = wx * (1.f - wy) * mf;
    float w01 = (1.f - wx) * wy * mf;
    float w11 = wx * wy * mf;
    const uint4* p = tfq + ((size_t)(v * PIX + ys * Ww + xs)) * 2;
    const uint4* q = p + Ww * 2;
    uint4 A = p[0], Ab = p[1], B = p[2], Bb = p[3];
    uint4 C = q[0], Cb = q[1], D = q[2], Db = q[3];
    acc16(A, w00, &acc[0]);
    acc8(Ab.x, Ab.y, w00, &acc[16]);
    acc16(B, w10, &acc[0]);
    acc8(Bb.x, Bb.y, w10, &acc[16]);
    acc16(C, w01, &acc[0]);
    acc8(Cb.x, Cb.y, w01, &acc[16]);
    acc16(D, w11, &acc[0]);
    acc8(Db.x, Db.y, w11, &acc[16]);
    zsum += mf * iz;
    cntf += mf;
  }

  float denom = fmaxf(cntf, 1.f);
  float invd = 1.f / denom;
  float z = zsum * invd;

  // h = pre_h[m] + (acc*invd) @ W_sp[0:24,:]
  float h[Cc];
  const float* ph = pre_h + (size_t)m * Cc;
#pragma unroll
  for (int j = 0; j < Cc; j++) h[j] = ph[j];
  for (int c = 0; c < Cc; c++) {
    float f = acc[c] * invd;
#pragma unroll
    for (int j = 0; j < Cc; j++) h[j] += f * Wl[c * Cc + j];
  }
#pragma unroll
  for (int j2 = 0; j2 < 12; j2++)
    hp[(size_t)j2 * Npts + n] = pack2h(h[2 * j2], h[2 * j2 + 1]);

  zbuf[n] = z;
  out[2 * Npts + n] = cntf;

  // reduction for zmean / znorm
  float rz = (z > 0.f) ? z : 0.f;
  float rz2 = rz * rz;
  float rcn = (z > 0.f) ? 1.f : 0.f;
#pragma unroll
  for (int off = 32; off > 0; off >>= 1) {
    rz += __shfl_down(rz, off);
    rz2 += __shfl_down(rz2, off);
    rcn += __shfl_down(rcn, off);
  }
  int wid = threadIdx.x >> 6, lid = threadIdx.x & 63;
  if (lid == 0) {
    redl[0][wid] = rz;
    redl[1][wid] = rz2;
    redl[2][wid] = rcn;
  }
  __syncthreads();
  if (threadIdx.x == 0) {
    float a = 0.f, b = 0.f, c = 0.f;
#pragma unroll
    for (int w = 0; w < 4; w++) {
      a += redl[0][w];
      b += redl[1][w];
      c += redl[2][w];
    }
    atomicAdd(&red[0], (double)a);
    atomicAdd(&red[1], (double)b);
    atomicAdd(&red[2], (double)c);
  }
}

// ---------------- 3) finalize: zn + relu + heads ---------------------------
__global__ __launch_bounds__(256) void final_kernel(
    const float* __restrict__ zbuf, const unsigned* __restrict__ hp,
    const float* __restrict__ W_sp, const float* __restrict__ W_t,
    const float* __restrict__ b_t, const float* __restrict__ W_o,
    const float* __restrict__ b_o, const double* __restrict__ red,
    float* __restrict__ out) {
  __shared__ float wz[Cc], wt[Cc], wo[Cc];
  __shared__ float bt, bo, s_zmean, s_izn;
  if (threadIdx.x < Cc) {
    wz[threadIdx.x] = W_sp[24 * Cc + threadIdx.x];
    wt[threadIdx.x] = W_t[threadIdx.x];
    wo[threadIdx.x] = W_o[threadIdx.x];
  }
  if (threadIdx.x == 0) {
    bt = b_t[0];
    bo = b_o[0];
    double sz = red[0], sz2 = red[1], cd = red[2];
    double npos = (cd > 0.0) ? cd : 1.0;
    double zmean = sz / npos;
    double var = sz2 - 2.0 * zmean * sz + cd * zmean * zmean;
    if (var < 0.0) var = 0.0;
    double znorm = sqrt(var) + 1e-5;
    s_zmean = (float)zmean;
    s_izn = (float)(1.0 / znorm);
  }
  __syncthreads();
  int n = blockIdx.x * 256 + threadIdx.x;
  float z = zbuf[n];
  float zn = (z > 0.f) ? (z - s_zmean) * s_izn : 0.f;
  float tsdf = bt, occ = bo;
#pragma unroll
  for (int j2 = 0; j2 < 12; j2++) {
    unsigned u = hp[(size_t)j2 * Npts + n];
    float2 f = __half22float2(*(const __half2*)&u);
    float h0 = fmaxf(f.x + zn * wz[2 * j2], 0.f);
    float h1 = fmaxf(f.y + zn * wz[2 * j2 + 1], 0.f);
    tsdf += h0 * wt[2 * j2] + h1 * wt[2 * j2 + 1];
    occ += h0 * wo[2 * j2] + h1 * wo[2 * j2 + 1];
  }
  ((float2*)out)[n] = make_float2(tsdf, occ);
}

// ---------------- launch ---------------------------------------------------
extern "C" void kernel_launch(void* const* d_in, const int* in_sizes, int n_in,
                              void* d_out, int out_size, void* d_ws,
                              size_t ws_size, hipStream_t stream) {
  const float* pre_feat = (const float*)d_in[0];
  const int* pre_coords = (const int*)d_in[1];
  const float* feats = (const float*)d_in[2];
  const float* KRcam = (const float*)d_in[3];
  const float* vol_origin = (const float*)d_in[4];
  const float* w2ac = (const float*)d_in[5];
  const float* W_sp = (const float*)d_in[6];
  const float* b_sp = (const float*)d_in[7];
  const float* W_t = (const float*)d_in[8];
  const float* b_t = (const float*)d_in[9];
  const float* W_o = (const float*)d_in[10];
  const float* b_o = (const float*)d_in[11];

  float* out = (float*)d_out;
  char* ws = (char*)d_ws;
  double* red = (double*)ws;
  uint4* tf = (uint4*)(ws + OFF_TF);
  float* pre_h = (float*)(ws + OFF_PREH);
  unsigned* hp = (unsigned*)(ws + OFF_HP);
  float* zbuf = (float*)(ws + OFF_Z);

  prep_kernel<<<Vv * 300 + Mpts / 256, 256, 0, stream>>>(feats, pre_feat, W_sp,
                                                         b_sp, tf, pre_h, red);
  main_kernel<<<Npts / 256, 256, 0, stream>>>(pre_coords, tf, KRcam,
                                              vol_origin, w2ac, W_sp, pre_h,
                                              out, hp, zbuf, red);
  final_kernel<<<Npts / 256, 256, 0, stream>>>(zbuf, hp, W_sp, W_t, b_t, W_o,
                                               b_o, red, out);
}

// Round 5
// 164.944 us; speedup vs baseline: 1.2934x; 1.2934x over previous
//
#include <hip/hip_runtime.h>
#include <hip/hip_fp16.h>

#define Mpts 32768
#define Vv 9
#define Cc 24
#define Hh 120
#define Ww 160
#define Npts (Mpts * 8)          // 262144
#define PIX (Hh * Ww)            // 19200
#define VOXEL 0.04f

// ---------------- workspace layout (bytes) ----------------
// [0,64)    : 3 doubles: sum_z, sum_z2, pos_cnt (zeroed by prep)
// OFF_TF    : tf = feats (V,H,W) x 32B/pixel fp8(24ch+8pad) : 5529600 B
// OFF_PREH  : pre_h (M,24) f32                               : 3145728 B
// OFF_HP    : hp (12,N) uint (= half2 channel pairs)         : 12582912 B
// OFF_Z     : zbuf (N) f32                                   : 1048576 B
#define OFF_TF    64
#define OFF_PREH  (OFF_TF + Vv * PIX * 32)
#define OFF_HP    (OFF_PREH + Mpts * Cc * 4)
#define OFF_Z     (OFF_HP + Npts * Cc * 2)

typedef __attribute__((ext_vector_type(2))) float f32x2;

__device__ __forceinline__ unsigned pack2h(float a, float b) {
  __half2 h = __floats2half2_rn(a, b);
  return *(unsigned*)&h;
}

// pack 4 floats -> 4 fp8 e4m3 in one uint
__device__ __forceinline__ unsigned pack4fp8(float a, float b, float c,
                                             float d) {
  int u = __builtin_amdgcn_cvt_pk_fp8_f32(a, b, 0, false);
  u = __builtin_amdgcn_cvt_pk_fp8_f32(c, d, u, true);
  return (unsigned)u;
}

// ---------------- 1) prep: feats -> fp8 (V,H,W,32B), pre_h, zero red -------
__global__ __launch_bounds__(256) void prep_kernel(
    const float* __restrict__ feats, const float* __restrict__ pre_feat,
    const float* __restrict__ W_sp, const float* __restrict__ b_sp,
    uint4* __restrict__ tf, float* __restrict__ pre_h,
    double* __restrict__ red) {
  __shared__ float tile[64][Cc + 1];
  __shared__ float Wl[50 * Cc];
  __shared__ float bl[Cc];
  int blk = blockIdx.x;
  if (blk == 0 && threadIdx.x < 3) red[threadIdx.x] = 0.0;

  if (blk < Vv * 300) {
    int v = blk / 300;
    int p0 = (blk % 300) * 64;
    const float* src = feats + (size_t)v * (Cc * PIX);
    for (int i = threadIdx.x; i < Cc * 64; i += 256) {
      int c = i >> 6, p = i & 63;
      tile[p][c] = src[c * PIX + p0 + p];
    }
    __syncthreads();
    uint4* dst = tf + ((size_t)v * PIX + p0) * 2;
    if (threadIdx.x < 128) {
      int p = threadIdx.x >> 1, sel = threadIdx.x & 1;
      const float* t = &tile[p][0];
      uint4 u;
      if (sel == 0) {
        u.x = pack4fp8(t[0], t[1], t[2], t[3]);
        u.y = pack4fp8(t[4], t[5], t[6], t[7]);
        u.z = pack4fp8(t[8], t[9], t[10], t[11]);
        u.w = pack4fp8(t[12], t[13], t[14], t[15]);
      } else {
        u.x = pack4fp8(t[16], t[17], t[18], t[19]);
        u.y = pack4fp8(t[20], t[21], t[22], t[23]);
        u.z = 0;
        u.w = 0;
      }
      dst[p * 2 + sel] = u;
    }
  } else {
    int mb = blk - Vv * 300;
    for (int i = threadIdx.x; i < 50 * Cc; i += 256) Wl[i] = W_sp[25 * Cc + i];
    if (threadIdx.x < Cc) bl[threadIdx.x] = b_sp[threadIdx.x];
    __syncthreads();
    int m = mb * 256 + threadIdx.x;
    float acc[Cc];
#pragma unroll
    for (int j = 0; j < Cc; j++) acc[j] = bl[j];
    const float* pf = pre_feat + (size_t)m * 50;
    for (int k = 0; k < 50; k++) {
      float x = pf[k];
#pragma unroll
      for (int j = 0; j < Cc; j++) acc[j] += x * Wl[k * Cc + j];
    }
    float* o = pre_h + (size_t)m * Cc;
#pragma unroll
    for (int j = 0; j < Cc; j++) o[j] = acc[j];
  }
}

// acc[0..15] += w * fp8x16(A)
__device__ __forceinline__ void acc16(uint4 A, float w, float* acc) {
#pragma unroll
  for (int t = 0; t < 4; t++) {
    unsigned u = ((const unsigned*)&A)[t];
    f32x2 f0 = __builtin_amdgcn_cvt_pk_f32_fp8((int)u, false);
    f32x2 f1 = __builtin_amdgcn_cvt_pk_f32_fp8((int)u, true);
    acc[4 * t + 0] += w * f0.x;
    acc[4 * t + 1] += w * f0.y;
    acc[4 * t + 2] += w * f1.x;
    acc[4 * t + 3] += w * f1.y;
  }
}
// acc[0..7] += w * fp8x8(ux,uy)
__device__ __forceinline__ void acc8v(unsigned ux, unsigned uy, float w,
                                      float* acc) {
  f32x2 f0 = __builtin_amdgcn_cvt_pk_f32_fp8((int)ux, false);
  f32x2 f1 = __builtin_amdgcn_cvt_pk_f32_fp8((int)ux, true);
  f32x2 f2 = __builtin_amdgcn_cvt_pk_f32_fp8((int)uy, false);
  f32x2 f3 = __builtin_amdgcn_cvt_pk_f32_fp8((int)uy, true);
  acc[0] += w * f0.x;
  acc[1] += w * f0.y;
  acc[2] += w * f1.x;
  acc[3] += w * f1.y;
  acc[4] += w * f2.x;
  acc[5] += w * f2.y;
  acc[6] += w * f3.x;
  acc[7] += w * f3.y;
}

// ---------------- 2) main: project + sample + h-partial + reduction --------
__global__ __launch_bounds__(256) void main_kernel(
    const int* __restrict__ pre_coords, const uint4* __restrict__ tfq,
    const float* __restrict__ KRcam, const float* __restrict__ vol_origin,
    const float* __restrict__ w2ac, const float* __restrict__ W_sp,
    const float* __restrict__ pre_h, float* __restrict__ out,
    unsigned* __restrict__ hp, float* __restrict__ zbuf,
    double* __restrict__ red) {
  __shared__ float KR[Vv * 12];
  __shared__ float w2a[12];
  __shared__ float orig[3];
  __shared__ float redl[3][4];
  for (int i = threadIdx.x; i < Vv * 12; i += 256) {
    int v = i / 12, r = i - v * 12;
    KR[i] = KRcam[v * 16 + r];
  }
  if (threadIdx.x < 12) w2a[threadIdx.x] = w2ac[threadIdx.x];
  if (threadIdx.x < 3) orig[threadIdx.x] = vol_origin[threadIdx.x];
  __syncthreads();

  int n = blockIdx.x * 256 + threadIdx.x;
  int m = n >> 3, o = n & 7;
  int cx = pre_coords[m * 4 + 1] + ((0xB2 >> o) & 1);
  int cy = pre_coords[m * 4 + 2] + ((0xD4 >> o) & 1);
  int cz = pre_coords[m * 4 + 3] + ((0xE8 >> o) & 1);
  float wx0 = (float)cx * VOXEL + orig[0];
  float wy0 = (float)cy * VOXEL + orig[1];
  float wz0 = (float)cz * VOXEL + orig[2];

  {  // r_coords
    float camx = w2a[0] * wx0 + w2a[1] * wy0 + w2a[2] * wz0 + w2a[3];
    float camy = w2a[4] * wx0 + w2a[5] * wy0 + w2a[6] * wz0 + w2a[7];
    float camz = w2a[8] * wx0 + w2a[9] * wy0 + w2a[10] * wz0 + w2a[11];
    float4 rc = make_float4(camx, camy, camz, (float)pre_coords[m * 4 + 0]);
    ((float4*)(out + 3 * Npts))[n] = rc;
  }

  float acc[Cc];
#pragma unroll
  for (int c = 0; c < Cc; c++) acc[c] = 0.f;
  float zsum = 0.f;
  int cnt = 0;

  for (int v = 0; v < Vv; v++) {
    const float* kr = &KR[v * 12];
    float ix = kr[0] * wx0 + kr[1] * wy0 + kr[2] * wz0 + kr[3];
    float iy = kr[4] * wx0 + kr[5] * wy0 + kr[6] * wz0 + kr[7];
    float iz = kr[8] * wx0 + kr[9] * wy0 + kr[10] * wz0 + kr[11];
    float sz = (fabsf(iz) > 1e-9f) ? iz : 1e-9f;
    float px = ix / sz;
    float py = iy / sz;
    bool msk = (px >= 0.f) && (px <= (float)(Ww - 1)) && (py >= 0.f) &&
               (py <= (float)(Hh - 1)) && (iz > 0.f);
    if (msk) {
      int x0 = (int)floorf(px), y0 = (int)floorf(py);
      int xs = min(x0, Ww - 2), ys = min(y0, Hh - 2);
      float wx = px - (float)xs, wy = py - (float)ys;
      float w00 = (1.f - wx) * (1.f - wy);
      float w10 = wx * (1.f - wy);
      float w01 = (1.f - wx) * wy;
      float w11 = wx * wy;
      const uint4* p = tfq + ((size_t)(v * PIX + ys * Ww + xs)) * 2;
      const uint4* q = p + Ww * 2;
      uint4 A = p[0], Ab = p[1], B = p[2], Bb = p[3];
      uint4 C = q[0], Cb = q[1], D = q[2], Db = q[3];
      acc16(A, w00, &acc[0]);
      acc8v(Ab.x, Ab.y, w00, &acc[16]);
      acc16(B, w10, &acc[0]);
      acc8v(Bb.x, Bb.y, w10, &acc[16]);
      acc16(C, w01, &acc[0]);
      acc8v(Cb.x, Cb.y, w01, &acc[16]);
      acc16(D, w11, &acc[0]);
      acc8v(Db.x, Db.y, w11, &acc[16]);
      zsum += iz;
      cnt++;
    }
  }

  float denom = fmaxf((float)cnt, 1.f);
  float invd = 1.f / denom;
  float z = zsum * invd;

  // h = pre_h[m] + (acc*invd) @ W_sp[0:24,:]
  // W_sp indices are thread-uniform compile-time offsets -> scalar loads.
  float h[Cc];
  const float* ph = pre_h + (size_t)m * Cc;
#pragma unroll
  for (int j = 0; j < Cc; j++) h[j] = ph[j];
#pragma unroll
  for (int c = 0; c < Cc; c++) {
    float f = acc[c] * invd;
#pragma unroll
    for (int j = 0; j < Cc; j++) h[j] += f * W_sp[c * Cc + j];
  }
#pragma unroll
  for (int j2 = 0; j2 < 12; j2++)
    hp[(size_t)j2 * Npts + n] = pack2h(h[2 * j2], h[2 * j2 + 1]);

  zbuf[n] = z;
  out[2 * Npts + n] = (float)cnt;

  // reduction for zmean / znorm
  float rz = (z > 0.f) ? z : 0.f;
  float rz2 = rz * rz;
  float rcn = (z > 0.f) ? 1.f : 0.f;
#pragma unroll
  for (int off = 32; off > 0; off >>= 1) {
    rz += __shfl_down(rz, off);
    rz2 += __shfl_down(rz2, off);
    rcn += __shfl_down(rcn, off);
  }
  int wid = threadIdx.x >> 6, lid = threadIdx.x & 63;
  if (lid == 0) {
    redl[0][wid] = rz;
    redl[1][wid] = rz2;
    redl[2][wid] = rcn;
  }
  __syncthreads();
  if (threadIdx.x == 0) {
    float a = 0.f, b = 0.f, c = 0.f;
#pragma unroll
    for (int w = 0; w < 4; w++) {
      a += redl[0][w];
      b += redl[1][w];
      c += redl[2][w];
    }
    atomicAdd(&red[0], (double)a);
    atomicAdd(&red[1], (double)b);
    atomicAdd(&red[2], (double)c);
  }
}

// ---------------- 3) finalize: zn + relu + heads ---------------------------
__global__ __launch_bounds__(256) void final_kernel(
    const float* __restrict__ zbuf, const unsigned* __restrict__ hp,
    const float* __restrict__ W_sp, const float* __restrict__ W_t,
    const float* __restrict__ b_t, const float* __restrict__ W_o,
    const float* __restrict__ b_o, const double* __restrict__ red,
    float* __restrict__ out) {
  __shared__ float wz[Cc], wt[Cc], wo[Cc];
  __shared__ float bt, bo, s_zmean, s_izn;
  if (threadIdx.x < Cc) {
    wz[threadIdx.x] = W_sp[24 * Cc + threadIdx.x];
    wt[threadIdx.x] = W_t[threadIdx.x];
    wo[threadIdx.x] = W_o[threadIdx.x];
  }
  if (threadIdx.x == 0) {
    bt = b_t[0];
    bo = b_o[0];
    double sz = red[0], sz2 = red[1], cd = red[2];
    double npos = (cd > 0.0) ? cd : 1.0;
    double zmean = sz / npos;
    double var = sz2 - 2.0 * zmean * sz + cd * zmean * zmean;
    if (var < 0.0) var = 0.0;
    double znorm = sqrt(var) + 1e-5;
    s_zmean = (float)zmean;
    s_izn = (float)(1.0 / znorm);
  }
  __syncthreads();
  int n = blockIdx.x * 256 + threadIdx.x;
  float z = zbuf[n];
  float zn = (z > 0.f) ? (z - s_zmean) * s_izn : 0.f;
  float tsdf = bt, occ = bo;
#pragma unroll
  for (int j2 = 0; j2 < 12; j2++) {
    unsigned u = hp[(size_t)j2 * Npts + n];
    float2 f = __half22float2(*(const __half2*)&u);
    float h0 = fmaxf(f.x + zn * wz[2 * j2], 0.f);
    float h1 = fmaxf(f.y + zn * wz[2 * j2 + 1], 0.f);
    tsdf += h0 * wt[2 * j2] + h1 * wt[2 * j2 + 1];
    occ += h0 * wo[2 * j2] + h1 * wo[2 * j2 + 1];
  }
  ((float2*)out)[n] = make_float2(tsdf, occ);
}

// ---------------- launch ---------------------------------------------------
extern "C" void kernel_launch(void* const* d_in, const int* in_sizes, int n_in,
                              void* d_out, int out_size, void* d_ws,
                              size_t ws_size, hipStream_t stream) {
  const float* pre_feat = (const float*)d_in[0];
  const int* pre_coords = (const int*)d_in[1];
  const float* feats = (const float*)d_in[2];
  const float* KRcam = (const float*)d_in[3];
  const float* vol_origin = (const float*)d_in[4];
  const float* w2ac = (const float*)d_in[5];
  const float* W_sp = (const float*)d_in[6];
  const float* b_sp = (const float*)d_in[7];
  const float* W_t = (const float*)d_in[8];
  const float* b_t = (const float*)d_in[9];
  const float* W_o = (const float*)d_in[10];
  const float* b_o = (const float*)d_in[11];

  float* out = (float*)d_out;
  char* ws = (char*)d_ws;
  double* red = (double*)ws;
  uint4* tf = (uint4*)(ws + OFF_TF);
  float* pre_h = (float*)(ws + OFF_PREH);
  unsigned* hp = (unsigned*)(ws + OFF_HP);
  float* zbuf = (float*)(ws + OFF_Z);

  prep_kernel<<<Vv * 300 + Mpts / 256, 256, 0, stream>>>(feats, pre_feat, W_sp,
                                                         b_sp, tf, pre_h, red);
  main_kernel<<<Npts / 256, 256, 0, stream>>>(pre_coords, tf, KRcam,
                                              vol_origin, w2ac, W_sp, pre_h,
                                              out, hp, zbuf, red);
  final_kernel<<<Npts / 256, 256, 0, stream>>>(zbuf, hp, W_sp, W_t, b_t, W_o,
                                               b_o, red, out);
}